// Round 1
// baseline (1737.956 us; speedup 1.0000x reference)
//
#include <hip/hip_runtime.h>

#define NN 20000
#define NE 600000
#define DIN 128
#define DD 64
#define HH 4
#define DKK 16
#define LL 4
#define TT 3
#define RR 32

// ---- monotone float<->uint encoding for atomicMax on signed floats ----
__device__ __forceinline__ unsigned enc_f(float x) {
    unsigned b = __float_as_uint(x);
    return (b & 0x80000000u) ? ~b : (b | 0x80000000u);
}
__device__ __forceinline__ float dec_f(unsigned u) {
    unsigned b = (u & 0x80000000u) ? (u & 0x7fffffffu) : ~u;
    return __uint_as_float(b);
}

__device__ __forceinline__ int src_nt(int e) { return e <= 9 ? 0 : (e <= 21 ? 1 : 2); }
__device__ __forceinline__ int dst_nt(int e) {
    if (e <= 2 || (e >= 10 && e <= 13) || (e >= 22 && e <= 24)) return 0;
    if ((e >= 3 && e <= 6) || (e >= 14 && e <= 17) || (e >= 25 && e <= 28)) return 1;
    return 2;
}

// ---- x = tanh(h @ adapt_W[ntype] + adapt_b[ntype]); wave per node ----
__global__ void adapt_kernel(const float* __restrict__ h, const int* __restrict__ ntype,
                             const float* __restrict__ W, const float* __restrict__ b,
                             float* __restrict__ x) {
    int wid = (blockIdx.x * blockDim.x + threadIdx.x) >> 6;
    int lane = threadIdx.x & 63;
    if (wid >= NN) return;
    int t = ntype[wid];
    const float* Wt = W + (size_t)t * DIN * DD;
    float h0 = h[(size_t)wid * DIN + lane];
    float h1 = h[(size_t)wid * DIN + 64 + lane];
    float acc = b[t * DD + lane];
#pragma unroll
    for (int d = 0; d < 64; ++d) {
        acc += __shfl(h0, d) * Wt[d * DD + lane];
    }
#pragma unroll
    for (int d = 0; d < 64; ++d) {
        acc += __shfl(h1, d) * Wt[(64 + d) * DD + lane];
    }
    x[(size_t)wid * DD + lane] = tanhf(acc);
}

// ---- k,q,v = x @ W*[ntype] + b*[ntype]; wave per node ----
__global__ void kqv_kernel(const float* __restrict__ x, const int* __restrict__ ntype,
                           const float* __restrict__ Wk, const float* __restrict__ bk,
                           const float* __restrict__ Wq, const float* __restrict__ bq,
                           const float* __restrict__ Wv, const float* __restrict__ bv,
                           float* __restrict__ k, float* __restrict__ q, float* __restrict__ v) {
    int wid = (blockIdx.x * blockDim.x + threadIdx.x) >> 6;
    int lane = threadIdx.x & 63;
    if (wid >= NN) return;
    int t = ntype[wid];
    const float* Wkt = Wk + (size_t)t * DD * DD;
    const float* Wqt = Wq + (size_t)t * DD * DD;
    const float* Wvt = Wv + (size_t)t * DD * DD;
    float xv = x[(size_t)wid * DD + lane];
    float ak = bk[t * DD + lane];
    float aq = bq[t * DD + lane];
    float av = bv[t * DD + lane];
#pragma unroll
    for (int d = 0; d < 64; ++d) {
        float xd = __shfl(xv, d);
        ak += xd * Wkt[d * DD + lane];
        aq += xd * Wqt[d * DD + lane];
        av += xd * Wvt[d * DD + lane];
    }
    k[(size_t)wid * DD + lane] = ak;
    q[(size_t)wid * DD + lane] = aq;
    v[(size_t)wid * DD + lane] = av;
}

// ---- pass A: per-edge logits + segment max; wave per edge, lane = (h,f) ----
__global__ void edge_logits_kernel(const float* __restrict__ k, const float* __restrict__ q,
                                   const int* __restrict__ src, const int* __restrict__ dst,
                                   const int* __restrict__ et,
                                   const float* __restrict__ relA, const float* __restrict__ pri,
                                   const float* __restrict__ nta, const float* __restrict__ nta1,
                                   const float* __restrict__ afc, const float* __restrict__ wgt,
                                   float* __restrict__ logits, unsigned* __restrict__ menc) {
    int e = (blockIdx.x * blockDim.x + threadIdx.x) >> 6;
    int lane = threadIdx.x & 63;
    if (e >= NE) return;
    int s = src[e], dd = dst[e], r = et[e];
    int hh = lane >> 4, f = lane & 15;
    float kv = k[(size_t)s * DD + lane];
    float qv = q[(size_t)dd * DD + lane];
    const float* A = relA + ((size_t)r * HH + hh) * DKK * DKK;
    int base = lane & 48;
    float key = 0.f;
#pragma unroll
    for (int d = 0; d < 16; ++d) {
        key += __shfl(kv, base + d) * A[d * DKK + f];
    }
    float prod = qv * key;
#pragma unroll
    for (int off = 1; off < 16; off <<= 1) prod += __shfl_xor(prod, off);
    float att = prod * pri[r * HH + hh] * 0.25f;
    float a_s = nta[src_nt(r)];
    float a_d = nta1[dst_nt(r)];
    float c = a_d * qv * afc[f] + a_s * kv * afc[16 + f];
#pragma unroll
    for (int off = 1; off < 16; off <<= 1) c += __shfl_xor(c, off);
    float na = c > 0.f ? c : 0.01f * c;
    float sw = 1.f / (1.f + expf(-wgt[0]));
    float lg = att + sw * na;
    if (f == 0) {
        logits[(size_t)e * HH + hh] = lg;
        atomicMax(&menc[((size_t)dd * RR + r) * HH + hh], enc_f(lg));
    }
}

// ---- pass B: ex = exp(logit - m); den += ex; thread per (e,h) ----
__global__ void softmax_den_kernel(const int* __restrict__ dst, const int* __restrict__ et,
                                   float* __restrict__ logits, const unsigned* __restrict__ menc,
                                   float* __restrict__ den) {
    int idx = blockIdx.x * blockDim.x + threadIdx.x;
    if (idx >= NE * HH) return;
    int e = idx >> 2, hh = idx & 3;
    int seg = (dst[e] * RR + et[e]) * HH + hh;
    float m = dec_f(menc[seg]);
    float ex = expf(logits[idx] - m);
    logits[idx] = ex;
    atomicAdd(&den[seg], ex);
}

// ---- pass C: t[dst] += (ex/den) * (v[src]^T rel_msg); wave per edge ----
__global__ void edge_accum_kernel(const float* __restrict__ v, const int* __restrict__ src,
                                  const int* __restrict__ dst, const int* __restrict__ et,
                                  const float* __restrict__ relM, const float* __restrict__ ex,
                                  const float* __restrict__ den, float* __restrict__ tacc) {
    int e = (blockIdx.x * blockDim.x + threadIdx.x) >> 6;
    int lane = threadIdx.x & 63;
    if (e >= NE) return;
    int s = src[e], dd = dst[e], r = et[e];
    int hh = lane >> 4, f = lane & 15;
    float vv = v[(size_t)s * DD + lane];
    const float* M = relM + ((size_t)r * HH + hh) * DKK * DKK;
    int base = lane & 48;
    float val = 0.f;
#pragma unroll
    for (int d = 0; d < 16; ++d) {
        val += __shfl(vv, base + d) * M[d * DKK + f];
    }
    int seg = (dd * RR + r) * HH + hh;
    float p = ex[(size_t)e * HH + hh] / den[seg];
    atomicAdd(&tacc[(size_t)dd * DD + lane], p * val);
}

// ---- node finalize: mean over present etypes, Wa, skip, layernorm ----
__global__ void node_out_kernel(const float* __restrict__ x_in, const float* __restrict__ tacc,
                                const float* __restrict__ den, const int* __restrict__ ntype,
                                const float* __restrict__ Wa, const float* __restrict__ ba,
                                const float* __restrict__ skipp,
                                const float* __restrict__ ln_g, const float* __restrict__ ln_b,
                                float* __restrict__ x_out) {
    int n = (blockIdx.x * blockDim.x + threadIdx.x) >> 6;
    int lane = threadIdx.x & 63;
    if (n >= NN) return;
    int t = ntype[n];
    int pres = 0;
    if (lane < RR) pres = (den[((size_t)n * RR + lane) * HH] > 0.f) ? 1 : 0;
    unsigned long long mask = __ballot(pres != 0);
    float cnt = (float)__popcll(mask);
    float divisor = fmaxf(cnt, 1.0f);
    float tv = tacc[(size_t)n * DD + lane] / divisor;
    const float* Wt = Wa + (size_t)t * DD * DD;
    float acc = ba[t * DD + lane];
#pragma unroll
    for (int d = 0; d < 64; ++d) {
        acc += __shfl(tv, d) * Wt[d * DD + lane];
    }
    float alpha = 1.f / (1.f + expf(-skipp[t]));
    float out = acc * alpha + x_in[(size_t)n * DD + lane] * (1.f - alpha);
    float s = out;
#pragma unroll
    for (int off = 1; off < 64; off <<= 1) s += __shfl_xor(s, off);
    float mu = s * (1.f / 64.f);
    float d0 = out - mu;
    float s2 = d0 * d0;
#pragma unroll
    for (int off = 1; off < 64; off <<= 1) s2 += __shfl_xor(s2, off);
    float var = s2 * (1.f / 64.f);
    float xn = d0 * rsqrtf(var + 1e-5f);
    x_out[(size_t)n * DD + lane] = xn * ln_g[t * DD + lane] + ln_b[t * DD + lane];
}

extern "C" void kernel_launch(void* const* d_in, const int* in_sizes, int n_in,
                              void* d_out, int out_size, void* d_ws, size_t ws_size,
                              hipStream_t stream) {
    const float* h       = (const float*)d_in[0];
    const int*   src     = (const int*)d_in[1];
    const int*   dst     = (const int*)d_in[2];
    const int*   etype   = (const int*)d_in[3];
    const int*   ntype   = (const int*)d_in[4];
    const float* adapt_W = (const float*)d_in[5];
    const float* adapt_b = (const float*)d_in[6];
    const float* Wk      = (const float*)d_in[7];
    const float* bk      = (const float*)d_in[8];
    const float* Wq      = (const float*)d_in[9];
    const float* bq      = (const float*)d_in[10];
    const float* Wv      = (const float*)d_in[11];
    const float* bv      = (const float*)d_in[12];
    const float* Wa      = (const float*)d_in[13];
    const float* ba      = (const float*)d_in[14];
    const float* ln_g    = (const float*)d_in[15];
    const float* ln_b    = (const float*)d_in[16];
    const float* rel_att = (const float*)d_in[17];
    const float* rel_msg = (const float*)d_in[18];
    const float* rel_pri = (const float*)d_in[19];
    const float* nta     = (const float*)d_in[20];
    const float* nta1    = (const float*)d_in[21];
    const float* skipp   = (const float*)d_in[22];
    const float* wgt     = (const float*)d_in[23];
    const float* afc_w   = (const float*)d_in[24];

    float* ws = (float*)d_ws;
    float* x0     = ws;                          // N*64
    float* x1     = x0 + (size_t)NN * DD;        // N*64
    float* kb     = x1 + (size_t)NN * DD;        // N*64
    float* qb     = kb + (size_t)NN * DD;        // N*64
    float* vb     = qb + (size_t)NN * DD;        // N*64
    float* tb     = vb + (size_t)NN * DD;        // N*64
    float* logits = tb + (size_t)NN * DD;        // E*4
    float* den    = logits + (size_t)NE * HH;    // N*R*4
    unsigned* menc = (unsigned*)(den + (size_t)NN * RR * HH);  // N*R*4

    const int NODE_BLOCKS = NN / 4;          // 5000 (4 waves of 64 per 256 block)
    const int EDGE_BLOCKS = NE / 4;          // 150000
    const int EH_BLOCKS   = (NE * HH) / 256; // 9375

    adapt_kernel<<<NODE_BLOCKS, 256, 0, stream>>>(h, ntype, adapt_W, adapt_b, x0);

    float* xin = x0;
    for (int l = 0; l < LL; ++l) {
        hipMemsetAsync(menc, 0, (size_t)NN * RR * HH * 4, stream);
        hipMemsetAsync(den, 0, (size_t)NN * RR * HH * 4, stream);
        hipMemsetAsync(tb, 0, (size_t)NN * DD * 4, stream);

        kqv_kernel<<<NODE_BLOCKS, 256, 0, stream>>>(
            xin, ntype,
            Wk + (size_t)l * TT * DD * DD, bk + (size_t)l * TT * DD,
            Wq + (size_t)l * TT * DD * DD, bq + (size_t)l * TT * DD,
            Wv + (size_t)l * TT * DD * DD, bv + (size_t)l * TT * DD,
            kb, qb, vb);

        edge_logits_kernel<<<EDGE_BLOCKS, 256, 0, stream>>>(
            kb, qb, src, dst, etype,
            rel_att + (size_t)l * RR * HH * DKK * DKK,
            rel_pri + (size_t)l * RR * HH,
            nta + (size_t)l * TT, nta1 + (size_t)l * TT,
            afc_w + (size_t)l * 2 * DKK, wgt + l,
            logits, menc);

        softmax_den_kernel<<<EH_BLOCKS, 256, 0, stream>>>(dst, etype, logits, menc, den);

        edge_accum_kernel<<<EDGE_BLOCKS, 256, 0, stream>>>(
            vb, src, dst, etype,
            rel_msg + (size_t)l * RR * HH * DKK * DKK,
            logits, den, tb);

        float* xout = (l == LL - 1) ? (float*)d_out : ((xin == x0) ? x1 : x0);
        node_out_kernel<<<NODE_BLOCKS, 256, 0, stream>>>(
            xin, tb, den, ntype,
            Wa + (size_t)l * TT * DD * DD, ba + (size_t)l * TT * DD,
            skipp + (size_t)l * TT,
            ln_g + (size_t)l * TT * DD, ln_b + (size_t)l * TT * DD,
            xout);
        xin = xout;
    }
}